// Round 8
// baseline (69.848 us; speedup 1.0000x reference)
//
#include <hip/hip_runtime.h>

// LinearAttention: B=4, H=8, L=4096, D=64, fp32 in/out.
// out = elu1(Q) @ KV / (elu1(Q)·Ksum + eps),  KV = elu1(K)^T @ V  (L-scalings cancel).
//
// K1 : 1024 blocks (32 heads x 32 chunks of 128 rows). LDS-staged 32-row tiles
//      (4 barriers/block), double-buffered, T14 split. fmap once at staging.
//      Lane (dq,vq) owns 8d x 8v; LDS reads 8-way broadcast conflict-free.
//      Reduce buffer ALIASED onto staging buffers (LDS = 32 KB).
// K1r: 160 blocks reduce 32 partials/head.
// K2 : 512 blocks (32 heads x 16 tiles of 256 rows). NO Q staging: lane owns
//      8 rows x 8 cols; Q streamed from global with 2-deep register dbuf;
//      KV+Ksum in LDS; den fused as packed f2. One barrier total.
//      NOTE: macro-internal index is dd4 — `const int d4 = (d4)` was UB (R7 bug).

#define LSEQ   4096
#define DDIM   64
#define NHEAD  32
#define K1CH   32
#define K1ROWS (LSEQ / K1CH)          // 128 rows per K1 block
#define T1ROWS 32                     // staged tile rows (K1)
#define NT1    (K1ROWS / T1ROWS)      // 4 tiles
#define WSPH   (DDIM * DDIM + DDIM)   // 4160 floats per partial / head
#define WSPH4  (WSPH / 4)             // 1040 float4

typedef float f2 __attribute__((ext_vector_type(2)));

__device__ __forceinline__ float fmap(float x) {
    return x > 0.0f ? (x + 1.0f) : __expf(x);   // elu(x)+1
}
__device__ __forceinline__ float4 fmap4(float4 v) {
    v.x = fmap(v.x); v.y = fmap(v.y); v.z = fmap(v.z); v.w = fmap(v.w);
    return v;
}
__device__ __forceinline__ f2 pkfma(f2 a, f2 b, f2 c) {
    return __builtin_elementwise_fma(a, b, c);   // -> v_pk_fma_f32
}

// ---------------- Kernel 1: partial KV[64][64] + Ksum[64] per (head,chunk) ----
__global__ __launch_bounds__(256) void la_kv_kernel(
    const float* __restrict__ Kg, const float* __restrict__ Vg,
    float* __restrict__ ws)
{
    // smem layout (floats): [0..2047] kst0 | [2048..4095] kst1
    //                       [4096..6143] vst0 | [6144..8191] vst1
    // After compute: red aliases [0..4095], kred aliases [4096..4159].
    __shared__ float smem[8192];

    const int t    = threadIdx.x;
    const int wave = t >> 6;
    const int lane = t & 63;
    const int dq   = lane >> 3;
    const int vq   = lane & 7;

    const int bh    = blockIdx.x / K1CH;
    const int chunk = blockIdx.x % K1CH;
    const size_t base = (size_t)bh * LSEQ * DDIM + (size_t)chunk * K1ROWS * DDIM;
    const float4* Kb4 = (const float4*)(Kg + base);
    const float4* Vb4 = (const float4*)(Vg + base);

    // stage tile 0 (512 float4 per tensor; thread handles t and t+256)
    {
        const float4 ka = Kb4[t], kb = Kb4[t + 256];
        const float4 va = Vb4[t], vb = Vb4[t + 256];
        ((float4*)smem)[t]       = fmap4(ka);
        ((float4*)smem)[t + 256] = fmap4(kb);
        ((float4*)(smem + 4096))[t]       = va;
        ((float4*)(smem + 4096))[t + 256] = vb;
    }
    __syncthreads();

    f2 acc[8][4];               // 8 d-rows x 8 v-cols (4 f2)
    f2 ksum2[4] = {(f2)(0.f), (f2)(0.f), (f2)(0.f), (f2)(0.f)};
#pragma unroll
    for (int i = 0; i < 8; ++i)
#pragma unroll
        for (int j = 0; j < 4; ++j) acc[i][j] = (f2)(0.0f);

#pragma unroll 1
    for (int tl = 0; tl < NT1; ++tl) {
        const int cur = tl & 1;
        const bool pre = (tl + 1 < NT1);
        float4 ka, kb, va, vb;
        if (pre) {                       // issue next tile's loads EARLY
            ka = Kb4[(tl + 1) * 512 + t];
            kb = Kb4[(tl + 1) * 512 + t + 256];
            va = Vb4[(tl + 1) * 512 + t];
            vb = Vb4[(tl + 1) * 512 + t + 256];
        }

        const float* kc = smem + cur * 2048;
        const float* vc = smem + 4096 + cur * 2048;
        // compute 8 rows of the current 32-row tile
#pragma unroll
        for (int r = 0; r < 8; ++r) {
            const int l = wave * 8 + r;
            const float4 k0 = *(const float4*)(kc + l * DDIM + dq * 8);
            const float4 k1 = *(const float4*)(kc + l * DDIM + dq * 8 + 4);
            const float4 v0 = *(const float4*)(vc + l * DDIM + vq * 4);
            const float4 v1 = *(const float4*)(vc + l * DDIM + 32 + vq * 4);
            const float kk[8] = {k0.x, k0.y, k0.z, k0.w, k1.x, k1.y, k1.z, k1.w};
            const f2 vv[4] = {{v0.x, v0.y}, {v0.z, v0.w}, {v1.x, v1.y}, {v1.z, v1.w}};
            ksum2[0] += (f2){kk[0], kk[1]};
            ksum2[1] += (f2){kk[2], kk[3]};
            ksum2[2] += (f2){kk[4], kk[5]};
            ksum2[3] += (f2){kk[6], kk[7]};
#pragma unroll
            for (int i = 0; i < 8; ++i) {
                const f2 ki = {kk[i], kk[i]};
#pragma unroll
                for (int j = 0; j < 4; ++j)
                    acc[i][j] = pkfma(ki, vv[j], acc[i][j]);
            }
        }

        if (pre) {                       // LDS-write AFTER compute
            float* kn = smem + (cur ^ 1) * 2048;
            float* vn = smem + 4096 + (cur ^ 1) * 2048;
            ((float4*)kn)[t]       = fmap4(ka);
            ((float4*)kn)[t + 256] = fmap4(kb);
            ((float4*)vn)[t]       = va;
            ((float4*)vn)[t + 256] = vb;
        }
        __syncthreads();
    }

    // cross-wave reduce in LDS (red aliases staging; barrier-protected),
    // chunk-XOR swizzle: phys f4-chunk = vq^dq.
    float4* red4 = (float4*)smem;          // 64x64 floats = 1024 f4
    float*  kred = smem + 4096;            // 64 floats
    for (int w = 0; w < 4; ++w) {
        __syncthreads();
        if (wave == w) {
            const int pj = vq ^ dq;
#pragma unroll
            for (int i = 0; i < 8; ++i) {
                const int d = dq * 8 + i;
                float4 lo = make_float4(acc[i][0].x, acc[i][0].y, acc[i][1].x, acc[i][1].y);
                float4 hi = make_float4(acc[i][2].x, acc[i][2].y, acc[i][3].x, acc[i][3].y);
                float4* plo = red4 + d * 16 + pj;
                float4* phi = red4 + d * 16 + 8 + pj;
                if (w != 0) {
                    const float4 a = *plo; const float4 b = *phi;
                    lo.x += a.x; lo.y += a.y; lo.z += a.z; lo.w += a.w;
                    hi.x += b.x; hi.y += b.y; hi.z += b.z; hi.w += b.w;
                }
                *plo = lo; *phi = hi;
            }
            if (vq == 0) {
                float* p = kred + dq * 8;
#pragma unroll
                for (int j = 0; j < 4; ++j) {
                    f2 s = ksum2[j];
                    if (w != 0) { s.x += p[2*j]; s.y += p[2*j+1]; }
                    p[2*j] = s.x; p[2*j+1] = s.y;
                }
            }
        }
    }
    __syncthreads();

    // coalesced store of the block's partial (undo the chunk swizzle)
    float4* dst = (float4*)(ws + (size_t)blockIdx.x * WSPH);
    for (int i = t; i < 1024; i += 256) {
        const int row = i >> 4, j = i & 15;
        const int pj = (((j & 7) ^ (row >> 3)) | (j & 8));
        dst[i] = red4[row * 16 + pj];
    }
    if (t < 16)
        dst[1024 + t] = ((const float4*)kred)[t];
}

// ---------------- Kernel 1r: reduce 32 partials per head -> final KV+Ksum ----
__global__ __launch_bounds__(256) void la_reduce_kernel(
    const float* __restrict__ ws, float* __restrict__ kvout)
{
    const int h   = blockIdx.x / 5;
    const int seg = blockIdx.x % 5;
    const int t   = threadIdx.x;
    if (t >= 208) return;
    const int i4 = seg * 208 + t;

    const float4* base = (const float4*)(ws + (size_t)h * K1CH * WSPH) + i4;
    float4 acc = make_float4(0.f, 0.f, 0.f, 0.f);
#pragma unroll 8
    for (int p = 0; p < K1CH; ++p) {
        const float4 x = base[(size_t)p * WSPH4];
        acc.x += x.x; acc.y += x.y; acc.z += x.z; acc.w += x.w;
    }
    ((float4*)(kvout + (size_t)h * WSPH))[i4] = acc;
}

// ---------------- Kernel 2: out = (Qf @ KV) / (Qf·Ksum + eps) -----------------
// 512 blocks (bh, tile of 256 rows), 256 threads. Lane owns rows
// {wave*64 + rg*8 + rr, rr=0..7} x cols {vq*8..+7}. Q from global (2-deep
// register dbuf); KV + Ksum from LDS; den fused (packed f2).
__global__ __launch_bounds__(256) void la_out_kernel(
    const float* __restrict__ Qg, const float* __restrict__ kvin,
    float* __restrict__ out)
{
    __shared__ float kvlds[DDIM * DDIM];
    __shared__ float ksl[DDIM];

    const int t    = threadIdx.x;
    const int wave = t >> 6;
    const int lane = t & 63;
    const int rg   = lane >> 3;
    const int vq   = lane & 7;

    const int bh   = blockIdx.x >> 4;
    const int tile = blockIdx.x & 15;
    const size_t base = (size_t)bh * LSEQ * DDIM + (size_t)tile * 256 * DDIM;
    const int row0 = wave * 64 + rg * 8;          // first of 8 rows this lane owns
    const float4* Qr4 = (const float4*)(Qg + base + (size_t)row0 * DDIM);
    float* Ob = out + base + (size_t)row0 * DDIM;

    // stage KV (1024 f4) + Ksum (16 f4)
    const float4* wsrc = (const float4*)(kvin + (size_t)bh * WSPH);
    for (int i = t; i < WSPH4; i += 256) {
        const float4 x = wsrc[i];
        if (i < 1024) ((float4*)kvlds)[i] = x;
        else          ((float4*)ksl)[i - 1024] = x;
    }
    __syncthreads();

    f2 acc[8][4];     // 8 rows x 8 cols
    f2 den2[8];
#pragma unroll
    for (int r = 0; r < 8; ++r) {
        den2[r] = (f2)(0.0f);
#pragma unroll
        for (int j = 0; j < 4; ++j) acc[r][j] = (f2)(0.0f);
    }

    float4 qA[8], qB[8];
#pragma unroll
    for (int r = 0; r < 8; ++r) qA[r] = Qr4[r * 16 + 0];

    // dd4: distinct name — `const int d4 = (d4)` self-initializes (UB, R7 bug)
#define K2_BODY(QBUF, D4)                                                     \
    {                                                                         \
        const int dd4 = (D4);                                                 \
        f2 kv[4][4];                                                          \
        _Pragma("unroll")                                                     \
        for (int i = 0; i < 4; ++i) {                                         \
            const float4 a = *(const float4*)(kvlds + (dd4*4+i)*DDIM + vq*8); \
            const float4 b = *(const float4*)(kvlds + (dd4*4+i)*DDIM + vq*8+4);\
            kv[i][0] = (f2){a.x, a.y}; kv[i][1] = (f2){a.z, a.w};             \
            kv[i][2] = (f2){b.x, b.y}; kv[i][3] = (f2){b.z, b.w};             \
        }                                                                     \
        const float4 ks4 = *(const float4*)(ksl + dd4 * 4);                   \
        const f2 ksa = {ks4.x, ks4.y}, ksb = {ks4.z, ks4.w};                  \
        _Pragma("unroll")                                                     \
        for (int r = 0; r < 8; ++r) {                                         \
            const float4 qf = fmap4(QBUF[r]);                                 \
            den2[r] = pkfma((f2){qf.x, qf.y}, ksa, den2[r]);                  \
            den2[r] = pkfma((f2){qf.z, qf.w}, ksb, den2[r]);                  \
            const float qa[4] = {qf.x, qf.y, qf.z, qf.w};                     \
            _Pragma("unroll")                                                 \
            for (int i = 0; i < 4; ++i) {                                     \
                const f2 qd = {qa[i], qa[i]};                                 \
                _Pragma("unroll")                                             \
                for (int j = 0; j < 4; ++j)                                   \
                    acc[r][j] = pkfma(qd, kv[i][j], acc[r][j]);               \
            }                                                                 \
        }                                                                     \
    }

#pragma unroll 1
    for (int d4 = 0; d4 < 16; d4 += 2) {
#pragma unroll
        for (int r = 0; r < 8; ++r) qB[r] = Qr4[r * 16 + (d4 + 1)];
        K2_BODY(qA, d4)
        if (d4 + 2 < 16) {
#pragma unroll
            for (int r = 0; r < 8; ++r) qA[r] = Qr4[r * 16 + (d4 + 2)];
        }
        K2_BODY(qB, d4 + 1)
    }
#undef K2_BODY

#pragma unroll
    for (int r = 0; r < 8; ++r) {
        const float den = den2[r].x + den2[r].y;
        const float z = 1.0f / (den + 1e-6f);
        float* orow = Ob + r * DDIM + vq * 8;
        const float4 lo = make_float4(acc[r][0].x * z, acc[r][0].y * z,
                                      acc[r][1].x * z, acc[r][1].y * z);
        const float4 hi = make_float4(acc[r][2].x * z, acc[r][2].y * z,
                                      acc[r][3].x * z, acc[r][3].y * z);
        *(float4*)(orow)     = lo;
        *(float4*)(orow + 4) = hi;
    }
}

extern "C" void kernel_launch(void* const* d_in, const int* in_sizes, int n_in,
                              void* d_out, int out_size, void* d_ws, size_t ws_size,
                              hipStream_t stream) {
    const float* q = (const float*)d_in[0];
    const float* k = (const float*)d_in[1];
    const float* v = (const float*)d_in[2];
    float* o  = (float*)d_out;
    float* ws = (float*)d_ws;
    float* kvfinal = ws + (size_t)NHEAD * K1CH * WSPH;

    hipLaunchKernelGGL(la_kv_kernel, dim3(NHEAD * K1CH), dim3(256), 0, stream,
                       k, v, ws);
    hipLaunchKernelGGL(la_reduce_kernel, dim3(NHEAD * 5), dim3(256), 0, stream,
                       ws, kvfinal);
    hipLaunchKernelGGL(la_out_kernel, dim3(NHEAD * 16), dim3(256), 0, stream,
                       q, kvfinal, o);
}